// Round 1
// baseline (241.571 us; speedup 1.0000x reference)
//
#include <hip/hip_runtime.h>
#include <math.h>

// Problem constants (from reference setup_inputs)
#define NB 32
#define NA 5
#define NC 20
#define NH 64
#define NW 64
#define MAXB 50
#define CPB (NA * NH * NW)   // cells per batch = 20480
#define NTOT (NB * CPB)      // 655360
#define SIL_THRESH 0.6f
#define OBJ_SCALE 5.0f

__device__ __forceinline__ float sigmoidf(float v) { return 1.0f / (1.0f + expf(-v)); }

__device__ __forceinline__ float iou_xywh(float x1, float y1, float w1, float h1,
                                          float x2, float y2, float w2, float h2) {
    float l = fmaxf(x1 - 0.5f * w1, x2 - 0.5f * w2);
    float r = fminf(x1 + 0.5f * w1, x2 + 0.5f * w2);
    float t = fmaxf(y1 - 0.5f * h1, y2 - 0.5f * h2);
    float b = fminf(y1 + 0.5f * h1, y2 + 0.5f * h2);
    float inter = fmaxf(r - l, 0.0f) * fmaxf(b - t, 0.0f);
    float uni = w1 * h1 + w2 * h2 - inter;
    return inter / fmaxf(uni, 1e-10f);
}

// Dense pass: default-target loss contribution for every (b, a, j, i) cell.
// Reads only channels 0..4 (x,y,w,h,conf) -> 13.1 MB of the 65.5 MB input.
__global__ __launch_bounds__(256) void region_dense(
        const float* __restrict__ out, const float* __restrict__ target,
        const float* __restrict__ anchors, float* __restrict__ loss) {
    __shared__ float s_gx[MAXB], s_gy[MAXB], s_gw[MAXB], s_gh[MAXB];
    __shared__ int s_nv;
    __shared__ float s_aw[NA], s_ah[NA];

    const int tid = threadIdx.x;
    const int n = blockIdx.x * 256 + tid;       // global cell index
    const int b = n / CPB;                      // 256 | CPB, so whole block is one batch

    // Compact valid GT boxes of this batch into LDS (thread 0, ~50 iters)
    if (tid == 0) {
        const float* tg = target + b * MAXB * 5;
        int nv = 0;
        for (int t = 0; t < MAXB; ++t) {
            float tx = tg[t * 5 + 1];
            if (tx > 0.0f) {
                s_gx[nv] = tx * NW;
                s_gy[nv] = tg[t * 5 + 2] * NH;
                s_gw[nv] = tg[t * 5 + 3] * NW;
                s_gh[nv] = tg[t * 5 + 4] * NH;
                ++nv;
            }
        }
        s_nv = nv;
    }
    if (tid < NA) { s_aw[tid] = anchors[2 * tid]; s_ah[tid] = anchors[2 * tid + 1]; }
    __syncthreads();

    const int r  = n - b * CPB;                 // within-batch cell
    const int a  = r >> 12;                     // / (NH*NW)
    const int ji = r & 4095;
    const int j  = ji >> 6;
    const int i  = ji & 63;

    const float* base = out + ((size_t)(b * 125 + a * 25) << 12) + ji;
    float xr = base[0];
    float yr = base[1 * 4096];
    float wr = base[2 * 4096];
    float hr = base[3 * 4096];
    float cr = base[4 * 4096];

    float x = sigmoidf(xr);
    float y = sigmoidf(yr);
    float conf = sigmoidf(cr);
    float px = x + (float)i;
    float py = y + (float)j;
    float pw = expf(wr) * s_aw[a];
    float ph = expf(hr) * s_ah[a];

    float maxi = 0.0f;
    const int nv = s_nv;
    for (int k = 0; k < nv; ++k) {
        float iou = iou_xywh(px, py, pw, ph, s_gx[k], s_gy[k], s_gw[k], s_gh[k]);
        maxi = fmaxf(maxi, iou);
    }
    float conf_base = (maxi > SIL_THRESH) ? 0.0f : 1.0f;  // NOOBJ_SCALE = 1

    float dx = x - 0.5f, dy = y - 0.5f;
    float v = 0.5f * (dx * dx + dy * dy + wr * wr + hr * hr)
            + 0.5f * conf_base * conf * conf;

    // wave64 reduce, one atomic per wave
    for (int off = 32; off; off >>= 1) v += __shfl_down(v, off);
    if ((tid & 63) == 0) atomicAdd(loss, v);
}

// Sparse pass: one block per batch; each valid GT box that wins its assigned
// cell (last-write-wins like numpy scatter) replaces default terms.
__global__ __launch_bounds__(64) void region_boxes(
        const float* __restrict__ out, const float* __restrict__ target,
        const float* __restrict__ anchors, float* __restrict__ loss) {
    const int b = blockIdx.x;
    const int tid = threadIdx.x;

    __shared__ float s_t[MAXB * 5];
    __shared__ int s_flat[MAXB];
    __shared__ float s_gx[MAXB], s_gy[MAXB], s_gw[MAXB], s_gh[MAXB];
    __shared__ int s_valid[MAXB];

    const float* tg = target + b * MAXB * 5;
    for (int idx = tid; idx < MAXB * 5; idx += 64) s_t[idx] = tg[idx];
    __syncthreads();

    float aw_[NA], ah_[NA];
    for (int q = 0; q < NA; ++q) { aw_[q] = anchors[2 * q]; ah_[q] = anchors[2 * q + 1]; }

    int myflat = -1, best_n = 0, gi = 0, gj = 0;
    float gx = 0, gy = 0, gw = 0, gh = 0, clsf = 0;
    if (tid < MAXB) {
        clsf = s_t[tid * 5 + 0];
        float xx = s_t[tid * 5 + 1];
        gx = xx * NW;
        gy = s_t[tid * 5 + 2] * NH;
        gw = s_t[tid * 5 + 3] * NW;
        gh = s_t[tid * 5 + 4] * NH;
        s_gx[tid] = gx; s_gy[tid] = gy; s_gw[tid] = gw; s_gh[tid] = gh;
        int valid = (xx > 0.0f) ? 1 : 0;
        s_valid[tid] = valid;
        if (valid) {
            float besti = -1.0f;
            for (int q = 0; q < NA; ++q) {           // first-max like jnp.argmax
                float inter = fminf(gw, aw_[q]) * fminf(gh, ah_[q]);
                float iou = inter / fmaxf(gw * gh + aw_[q] * ah_[q] - inter, 1e-10f);
                if (iou > besti) { besti = iou; best_n = q; }
            }
            gi = min(max((int)floorf(gx), 0), NW - 1);
            gj = min(max((int)floorf(gy), 0), NH - 1);
            myflat = (best_n << 12) + (gj << 6) + gi;
        }
        s_flat[tid] = myflat;
    }
    __syncthreads();

    bool winner = (myflat >= 0);
    if (winner) {
        for (int t2 = tid + 1; t2 < MAXB; ++t2)
            if (s_flat[t2] == myflat) { winner = false; break; }
    }
    if (!winner) return;

    const float* basep = out + ((size_t)(b * 125 + best_n * 25) << 12) + (gj << 6) + gi;
    float xr = basep[0];
    float yr = basep[1 * 4096];
    float wr = basep[2 * 4096];
    float hr = basep[3 * 4096];
    float cr = basep[4 * 4096];

    float x = sigmoidf(xr);
    float y = sigmoidf(yr);
    float conf = sigmoidf(cr);
    float px = x + (float)gi;
    float py = y + (float)gj;
    float pw = expf(wr) * aw_[best_n];
    float ph = expf(hr) * ah_[best_n];

    // conf_base at this cell (same as dense pass computed)
    float maxi = 0.0f;
    for (int k = 0; k < MAXB; ++k) {
        if (s_valid[k]) {
            float iou = iou_xywh(px, py, pw, ph, s_gx[k], s_gy[k], s_gw[k], s_gh[k]);
            maxi = fmaxf(maxi, iou);
        }
    }
    float conf_base = (maxi > SIL_THRESH) ? 0.0f : 1.0f;

    float txv = gx - (float)gi;
    float tyv = gy - (float)gj;
    float twv = logf(fmaxf(gw, 1e-10f) / aw_[best_n]);
    float thv = logf(fmaxf(gh, 1e-10f) / ah_[best_n]);
    float tconf = iou_xywh(gx, gy, gw, gh, px, py, pw, ph);

    float dxn = x - txv, dyn = y - tyv, dwn = wr - twv, dhn = hr - thv;
    float dxo = x - 0.5f, dyo = y - 0.5f;
    float dc = conf - tconf;

    float delta = 0.5f * ((dxn * dxn - dxo * dxo) + (dyn * dyn - dyo * dyo)
                        + (dwn * dwn - wr * wr) + (dhn * dhn - hr * hr))
                + 0.5f * (OBJ_SCALE * dc * dc - conf_base * conf * conf);

    // class NLL at this cell: -log_softmax(logits)[cls]
    const float* cl = basep + 5 * 4096;
    int ci = (int)clsf;
    float m = -INFINITY;
    for (int c = 0; c < NC; ++c) m = fmaxf(m, cl[c * 4096]);
    float s = 0.0f;
    for (int c = 0; c < NC; ++c) s += expf(cl[c * 4096] - m);
    float picked = cl[ci * 4096] - m - logf(s);
    delta -= picked;

    atomicAdd(loss, delta);
}

extern "C" void kernel_launch(void* const* d_in, const int* in_sizes, int n_in,
                              void* d_out, int out_size, void* d_ws, size_t ws_size,
                              hipStream_t stream) {
    (void)in_sizes; (void)n_in; (void)d_ws; (void)ws_size;
    const float* output  = (const float*)d_in[0];
    const float* target  = (const float*)d_in[1];
    const float* anchors = (const float*)d_in[2];
    float* loss = (float*)d_out;

    hipMemsetAsync(loss, 0, (size_t)out_size * sizeof(float), stream);
    region_dense<<<NTOT / 256, 256, 0, stream>>>(output, target, anchors, loss);
    region_boxes<<<NB, 64, 0, stream>>>(output, target, anchors, loss);
}

// Round 2
// 124.788 us; speedup vs baseline: 1.9359x; 1.9359x over previous
//
#include <hip/hip_runtime.h>
#include <math.h>

// Problem constants (from reference setup_inputs)
#define NB 32
#define NA 5
#define NC 20
#define NH 64
#define NW 64
#define MAXB 50
#define CPB (NA * NH * NW)   // cells per batch = 20480
#define NTOT (NB * CPB)      // 655360
#define NBLK_DENSE (NTOT / 256)   // 2560
#define NPART (NBLK_DENSE + NB)   // 2592 partials in d_ws
#define SIL_THRESH 0.6f
#define OBJ_SCALE 5.0f

__device__ __forceinline__ float sigmoidf(float v) { return 1.0f / (1.0f + expf(-v)); }

__device__ __forceinline__ float iou_xywh(float x1, float y1, float w1, float h1,
                                          float x2, float y2, float w2, float h2) {
    float l = fmaxf(x1 - 0.5f * w1, x2 - 0.5f * w2);
    float r = fminf(x1 + 0.5f * w1, x2 + 0.5f * w2);
    float t = fmaxf(y1 - 0.5f * h1, y2 - 0.5f * h2);
    float b = fminf(y1 + 0.5f * h1, y2 + 0.5f * h2);
    float inter = fmaxf(r - l, 0.0f) * fmaxf(b - t, 0.0f);
    float uni = w1 * h1 + w2 * h2 - inter;
    return inter / fmaxf(uni, 1e-10f);
}

// Dense pass: default-target loss contribution for every (b, a, j, i) cell.
// Reads only channels 0..4 (x,y,w,h,conf). Writes ONE partial per block to ws.
__global__ __launch_bounds__(256) void region_dense(
        const float* __restrict__ out, const float* __restrict__ target,
        const float* __restrict__ anchors, float* __restrict__ ws) {
    __shared__ float s_gx[MAXB], s_gy[MAXB], s_gw[MAXB], s_gh[MAXB];
    __shared__ int s_nv;
    __shared__ float s_aw[NA], s_ah[NA];
    __shared__ float s_part[4];

    const int tid = threadIdx.x;
    const int n = blockIdx.x * 256 + tid;       // global cell index
    const int b = n / CPB;                      // 256 | CPB, so whole block is one batch

    // Compact valid GT boxes of this batch into LDS (thread 0, 50 iters, L2-hot)
    if (tid == 0) {
        const float* tg = target + b * MAXB * 5;
        int nv = 0;
        for (int t = 0; t < MAXB; ++t) {
            float tx = tg[t * 5 + 1];
            if (tx > 0.0f) {
                s_gx[nv] = tx * NW;
                s_gy[nv] = tg[t * 5 + 2] * NH;
                s_gw[nv] = tg[t * 5 + 3] * NW;
                s_gh[nv] = tg[t * 5 + 4] * NH;
                ++nv;
            }
        }
        s_nv = nv;
    }
    if (tid < NA) { s_aw[tid] = anchors[2 * tid]; s_ah[tid] = anchors[2 * tid + 1]; }
    __syncthreads();

    const int r  = n - b * CPB;                 // within-batch cell
    const int a  = r >> 12;                     // / (NH*NW)
    const int ji = r & 4095;
    const int j  = ji >> 6;
    const int i  = ji & 63;

    const float* base = out + ((size_t)(b * 125 + a * 25) << 12) + ji;
    float xr = base[0];
    float yr = base[1 * 4096];
    float wr = base[2 * 4096];
    float hr = base[3 * 4096];
    float cr = base[4 * 4096];

    float x = sigmoidf(xr);
    float y = sigmoidf(yr);
    float conf = sigmoidf(cr);
    float px = x + (float)i;
    float py = y + (float)j;
    float pw = expf(wr) * s_aw[a];
    float ph = expf(hr) * s_ah[a];

    float maxi = 0.0f;
    const int nv = s_nv;
    for (int k = 0; k < nv; ++k) {
        float iou = iou_xywh(px, py, pw, ph, s_gx[k], s_gy[k], s_gw[k], s_gh[k]);
        maxi = fmaxf(maxi, iou);
    }
    float conf_base = (maxi > SIL_THRESH) ? 0.0f : 1.0f;  // NOOBJ_SCALE = 1

    float dx = x - 0.5f, dy = y - 0.5f;
    float v = 0.5f * (dx * dx + dy * dy + wr * wr + hr * hr)
            + 0.5f * conf_base * conf * conf;

    // wave64 shfl reduce -> 4 wave leaders -> LDS -> thread 0 stores partial
    for (int off = 32; off; off >>= 1) v += __shfl_down(v, off);
    if ((tid & 63) == 0) s_part[tid >> 6] = v;
    __syncthreads();
    if (tid == 0)
        ws[blockIdx.x] = s_part[0] + s_part[1] + s_part[2] + s_part[3];
}

// Sparse pass: one block per batch; each valid GT box that wins its assigned
// cell (last-write-wins like numpy scatter) replaces default terms.
// Writes ONE partial per block to ws[NBLK_DENSE + b].
__global__ __launch_bounds__(64) void region_boxes(
        const float* __restrict__ out, const float* __restrict__ target,
        const float* __restrict__ anchors, float* __restrict__ ws) {
    const int b = blockIdx.x;
    const int tid = threadIdx.x;

    __shared__ float s_t[MAXB * 5];
    __shared__ int s_flat[MAXB];
    __shared__ float s_gx[MAXB], s_gy[MAXB], s_gw[MAXB], s_gh[MAXB];
    __shared__ int s_valid[MAXB];

    const float* tg = target + b * MAXB * 5;
    for (int idx = tid; idx < MAXB * 5; idx += 64) s_t[idx] = tg[idx];
    __syncthreads();

    float aw_[NA], ah_[NA];
    for (int q = 0; q < NA; ++q) { aw_[q] = anchors[2 * q]; ah_[q] = anchors[2 * q + 1]; }

    int myflat = -1, best_n = 0, gi = 0, gj = 0;
    float gx = 0, gy = 0, gw = 0, gh = 0, clsf = 0;
    if (tid < MAXB) {
        clsf = s_t[tid * 5 + 0];
        float xx = s_t[tid * 5 + 1];
        gx = xx * NW;
        gy = s_t[tid * 5 + 2] * NH;
        gw = s_t[tid * 5 + 3] * NW;
        gh = s_t[tid * 5 + 4] * NH;
        s_gx[tid] = gx; s_gy[tid] = gy; s_gw[tid] = gw; s_gh[tid] = gh;
        int valid = (xx > 0.0f) ? 1 : 0;
        s_valid[tid] = valid;
        if (valid) {
            float besti = -1.0f;
            for (int q = 0; q < NA; ++q) {           // first-max like jnp.argmax
                float inter = fminf(gw, aw_[q]) * fminf(gh, ah_[q]);
                float iou = inter / fmaxf(gw * gh + aw_[q] * ah_[q] - inter, 1e-10f);
                if (iou > besti) { besti = iou; best_n = q; }
            }
            gi = min(max((int)floorf(gx), 0), NW - 1);
            gj = min(max((int)floorf(gy), 0), NH - 1);
            myflat = (best_n << 12) + (gj << 6) + gi;
        }
        s_flat[tid] = myflat;
    } else {
        s_flat[tid < MAXB ? tid : 0] = s_flat[tid < MAXB ? tid : 0]; // no-op
    }
    __syncthreads();

    // last-write-wins: a box is the winner iff no HIGHER-index box maps to same cell
    bool winner = (myflat >= 0);
    if (winner) {
        for (int t2 = tid + 1; t2 < MAXB; ++t2)
            if (s_flat[t2] == myflat) { winner = false; break; }
    }

    float delta = 0.0f;
    if (winner) {
        const float* basep = out + ((size_t)(b * 125 + best_n * 25) << 12) + (gj << 6) + gi;
        float xr = basep[0];
        float yr = basep[1 * 4096];
        float wr = basep[2 * 4096];
        float hr = basep[3 * 4096];
        float cr = basep[4 * 4096];

        float x = sigmoidf(xr);
        float y = sigmoidf(yr);
        float conf = sigmoidf(cr);
        float px = x + (float)gi;
        float py = y + (float)gj;
        float pw = expf(wr) * aw_[best_n];
        float ph = expf(hr) * ah_[best_n];

        // conf_base at this cell (same value the dense pass used)
        float maxi = 0.0f;
        for (int k = 0; k < MAXB; ++k) {
            if (s_valid[k]) {
                float iou = iou_xywh(px, py, pw, ph, s_gx[k], s_gy[k], s_gw[k], s_gh[k]);
                maxi = fmaxf(maxi, iou);
            }
        }
        float conf_base = (maxi > SIL_THRESH) ? 0.0f : 1.0f;

        float txv = gx - (float)gi;
        float tyv = gy - (float)gj;
        float twv = logf(fmaxf(gw, 1e-10f) / aw_[best_n]);
        float thv = logf(fmaxf(gh, 1e-10f) / ah_[best_n]);
        float tconf = iou_xywh(gx, gy, gw, gh, px, py, pw, ph);

        float dxn = x - txv, dyn = y - tyv, dwn = wr - twv, dhn = hr - thv;
        float dxo = x - 0.5f, dyo = y - 0.5f;
        float dc = conf - tconf;

        delta = 0.5f * ((dxn * dxn - dxo * dxo) + (dyn * dyn - dyo * dyo)
                      + (dwn * dwn - wr * wr) + (dhn * dhn - hr * hr))
              + 0.5f * (OBJ_SCALE * dc * dc - conf_base * conf * conf);

        // class NLL at this cell: -log_softmax(logits)[cls]
        const float* cl = basep + 5 * 4096;
        int ci = (int)clsf;
        float m = -INFINITY;
        for (int c = 0; c < NC; ++c) m = fmaxf(m, cl[c * 4096]);
        float s = 0.0f;
        for (int c = 0; c < NC; ++c) s += expf(cl[c * 4096] - m);
        float picked = cl[ci * 4096] - m - logf(s);
        delta -= picked;
    }

    // single-wave (64-thread) shfl reduce, one plain store per block
    for (int off = 32; off; off >>= 1) delta += __shfl_down(delta, off);
    if (tid == 0) ws[NBLK_DENSE + b] = delta;
}

// Final reduction: sum NPART partials -> d_out[0]
__global__ __launch_bounds__(256) void region_reduce(
        const float* __restrict__ ws, float* __restrict__ loss) {
    __shared__ float s_part[4];
    const int tid = threadIdx.x;
    float v = 0.0f;
    for (int idx = tid; idx < NPART; idx += 256) v += ws[idx];
    for (int off = 32; off; off >>= 1) v += __shfl_down(v, off);
    if ((tid & 63) == 0) s_part[tid >> 6] = v;
    __syncthreads();
    if (tid == 0) loss[0] = s_part[0] + s_part[1] + s_part[2] + s_part[3];
}

extern "C" void kernel_launch(void* const* d_in, const int* in_sizes, int n_in,
                              void* d_out, int out_size, void* d_ws, size_t ws_size,
                              hipStream_t stream) {
    (void)in_sizes; (void)n_in; (void)ws_size; (void)out_size;
    const float* output  = (const float*)d_in[0];
    const float* target  = (const float*)d_in[1];
    const float* anchors = (const float*)d_in[2];
    float* ws = (float*)d_ws;
    float* loss = (float*)d_out;

    region_dense<<<NBLK_DENSE, 256, 0, stream>>>(output, target, anchors, ws);
    region_boxes<<<NB, 64, 0, stream>>>(output, target, anchors, ws);
    region_reduce<<<1, 256, 0, stream>>>(ws, loss);
}